// Round 2
// baseline (700.285 us; speedup 1.0000x reference)
//
#include <hip/hip_runtime.h>

typedef __bf16 bf16;
typedef __bf16 bf16x4 __attribute__((ext_vector_type(4)));
typedef __bf16 bf16x8 __attribute__((ext_vector_type(8)));
typedef float f32x4 __attribute__((ext_vector_type(4)));
typedef float floatx4 __attribute__((ext_vector_type(4)));

#define S 96
#define DIN 768
#define DOUT 256
#define MROWS 73728  // 8*96*96

__device__ static inline void async16(const bf16* g, bf16* l) {
    __builtin_amdgcn_global_load_lds(
        (const __attribute__((address_space(1))) void*)g,
        (__attribute__((address_space(3))) void*)l,
        16, 0, 0);
}

// ---------------------------------------------------------------------------
// gether1: X = gether(H) + H  (coefficient 2 on center row). fp32 in, bf16 out
// one block per (b,l)
// ---------------------------------------------------------------------------
__global__ __launch_bounds__(256) void k_gether1(
    const float* __restrict__ H, const float* __restrict__ Asim,
    const float* __restrict__ Tsim, const float* __restrict__ Adj,
    bf16* __restrict__ X)
{
    __shared__ float adjs[S];
    __shared__ float ts[S];
    __shared__ float diagf[DIN];
    int b = blockIdx.x / S, l = blockIdx.x % S;
    int tid = threadIdx.x;
    long row0 = (long)(b * S + l) * S;
    if (tid < S) {
        adjs[tid] = Adj[(b * S + l) * S + tid];
        ts[tid]   = Tsim[b * S + tid];
    }
    for (int i = tid; i < DIN / 4; i += 256)
        *(f32x4*)&diagf[i * 4] = *(const f32x4*)&H[(row0 + l) * DIN + i * 4];
    float a_up = (l > 0)     ? Asim[b * S + l - 1] : 0.f;
    float a_dn = (l < S - 1) ? Asim[b * S + l + 1] : 0.f;
    long du = (l > 0)     ? -(long)S * DIN : 0;
    long dd = (l < S - 1) ?  (long)S * DIN : 0;
    __syncthreads();

    for (int it = tid; it < S * (DIN / 4); it += 256) {
        int k = it / (DIN / 4);
        int c = it - k * (DIN / 4);
        const float* hc = H + (row0 + k) * DIN + c * 4;
        float tl = (k > 0)     ? ts[k - 1] : 0.f;
        float tr = (k < S - 1) ? ts[k + 1] : 0.f;
        long  dl = (k > 0)     ? -(long)DIN : 0;
        long  dr = (k < S - 1) ?  (long)DIN : 0;
        f32x4 vc = *(const f32x4*)hc;
        f32x4 vl = *(const f32x4*)(hc + dl);
        f32x4 vr = *(const f32x4*)(hc + dr);
        f32x4 vu = *(const f32x4*)(hc + du);
        f32x4 vd = *(const f32x4*)(hc + dd);
        float aj = adjs[k];
        bf16x4 o;
#pragma unroll
        for (int j = 0; j < 4; ++j) {
            float v = 2.f * vc[j] + aj * diagf[c * 4 + j]
                    + tl * vl[j] + tr * vr[j]
                    + a_up * vu[j] + a_dn * vd[j];
            o[j] = (bf16)v;
        }
        *(bf16x4*)&X[(row0 + k) * DIN + c * 4] = o;
    }
}

// ---------------------------------------------------------------------------
// gether2: sources are h1 = relu(g1 * y * invr) reconstructed on the fly.
// Y is bf16 (pre-norm GEMM1 output), out X bf16.
// ---------------------------------------------------------------------------
__global__ __launch_bounds__(256) void k_gether2(
    const bf16* __restrict__ Y, const float* __restrict__ INV,
    const float* __restrict__ G1, const float* __restrict__ Asim,
    const float* __restrict__ Tsim, const float* __restrict__ Adj,
    bf16* __restrict__ X)
{
    __shared__ float adjs[S];
    __shared__ float ts[S];
    __shared__ float diagf[DIN];
    __shared__ float g1s[DIN];
    int b = blockIdx.x / S, l = blockIdx.x % S;
    int tid = threadIdx.x;
    long row0 = (long)(b * S + l) * S;
    for (int i = tid; i < DIN; i += 256) g1s[i] = G1[i];
    __syncthreads();
    if (tid < S) {
        adjs[tid] = Adj[(b * S + l) * S + tid];
        ts[tid]   = Tsim[b * S + tid];
        float iv = INV[row0 + l];
        bf16x8 yv = *(const bf16x8*)&Y[(row0 + l) * DIN + tid * 8];
#pragma unroll
        for (int j = 0; j < 8; ++j) {
            float v = g1s[tid * 8 + j] * (float)yv[j] * iv;
            diagf[tid * 8 + j] = v > 0.f ? v : 0.f;
        }
    }
    float a_up = (l > 0)     ? Asim[b * S + l - 1] : 0.f;
    float a_dn = (l < S - 1) ? Asim[b * S + l + 1] : 0.f;
    long du = (l > 0)     ? -(long)S * DIN : 0;
    long dd = (l < S - 1) ?  (long)S * DIN : 0;
    int ou = (l > 0) ? -S : 0;
    int od = (l < S - 1) ? S : 0;
    __syncthreads();

    for (int it = tid; it < S * (DIN / 8); it += 256) {
        int k = it / (DIN / 8);
        int c = it - k * (DIN / 8);
        const bf16* yc = Y + (row0 + k) * DIN + c * 8;
        float tl = (k > 0)     ? ts[k - 1] : 0.f;
        float tr = (k < S - 1) ? ts[k + 1] : 0.f;
        int   ol = (k > 0)     ? -1 : 0;
        int   orr = (k < S - 1) ? 1 : 0;
        float ivc = INV[row0 + k];
        float ivl = INV[row0 + k + ol];
        float ivr = INV[row0 + k + orr];
        float ivu = INV[row0 + k + ou];
        float ivd = INV[row0 + k + od];
        bf16x8 vc = *(const bf16x8*)yc;
        bf16x8 vl = *(const bf16x8*)(yc + (long)ol * DIN);
        bf16x8 vr = *(const bf16x8*)(yc + (long)orr * DIN);
        bf16x8 vu = *(const bf16x8*)(yc + du);
        bf16x8 vd = *(const bf16x8*)(yc + dd);
        float aj = adjs[k];
        bf16x8 o;
#pragma unroll
        for (int j = 0; j < 8; ++j) {
            float g = g1s[c * 8 + j];
            float hc_ = g * (float)vc[j] * ivc; hc_ = hc_ > 0.f ? hc_ : 0.f;
            float hl_ = g * (float)vl[j] * ivl; hl_ = hl_ > 0.f ? hl_ : 0.f;
            float hr_ = g * (float)vr[j] * ivr; hr_ = hr_ > 0.f ? hr_ : 0.f;
            float hu_ = g * (float)vu[j] * ivu; hu_ = hu_ > 0.f ? hu_ : 0.f;
            float hd_ = g * (float)vd[j] * ivd; hd_ = hd_ > 0.f ? hd_ : 0.f;
            float v = 2.f * hc_ + aj * diagf[c * 8 + j]
                    + tl * hl_ + tr * hr_ + a_up * hu_ + a_dn * hd_;
            o[j] = (bf16)v;
        }
        *(bf16x8*)&X[(row0 + k) * DIN + c * 8] = o;
    }
}

// ---------------------------------------------------------------------------
// GEMM: Y[M x N] = X[M x 768] @ WT[N x 768]^T + bias ; ssq[r] += sum(y^2)
// 128x128 tile, BK=32, 4 waves each 64x64 (4x4 frags of 16x16x32 bf16 MFMA)
// blockIdx.x = col tile, blockIdx.y = row tile
// ---------------------------------------------------------------------------
template <int N, typename OutT>
__global__ __launch_bounds__(256) void k_gemm(
    const bf16* __restrict__ Xm, const bf16* __restrict__ WT,
    const float* __restrict__ bias, OutT* __restrict__ Y,
    float* __restrict__ ssq)
{
    constexpr int K = 768;
    __shared__ __align__(16) bf16 As[128 * 32];
    __shared__ __align__(16) bf16 Bs[128 * 32];
    int t = threadIdx.x;
    int colBase = blockIdx.x * 128;
    int rowBase = blockIdx.y * 128;
    int lane = t & 63, w = t >> 6;
    int quad = lane >> 4, l16 = lane & 15;
    int wr = w >> 1, wc = w & 1;

    floatx4 acc[4][4];
#pragma unroll
    for (int i = 0; i < 4; ++i)
#pragma unroll
        for (int j = 0; j < 4; ++j) acc[i][j] = (floatx4)0.f;

    const bf16* gA = Xm + (size_t)(rowBase + (t >> 2)) * K + (t & 3) * 8;
    const bf16* gB = WT + (size_t)(colBase + (t >> 2)) * K + (t & 3) * 8;
    bf16* ldsA = &As[t * 8];
    bf16* ldsB = &Bs[t * 8];

    for (int kk = 0; kk < K; kk += 32) {
        __syncthreads();
        async16(gA + kk, ldsA);
        async16(gA + kk + 64 * K, ldsA + 2048);
        async16(gB + kk, ldsB);
        async16(gB + kk + 64 * K, ldsB + 2048);
        __syncthreads();
        bf16x8 af[4], bfr[4];
#pragma unroll
        for (int i = 0; i < 4; ++i)
            af[i] = *(const bf16x8*)&As[(wr * 64 + i * 16 + l16) * 32 + quad * 8];
#pragma unroll
        for (int i = 0; i < 4; ++i)
            bfr[i] = *(const bf16x8*)&Bs[(wc * 64 + i * 16 + l16) * 32 + quad * 8];
#pragma unroll
        for (int i = 0; i < 4; ++i)
#pragma unroll
            for (int j = 0; j < 4; ++j)
                acc[i][j] = __builtin_amdgcn_mfma_f32_16x16x32_bf16(
                    af[i], bfr[j], acc[i][j], 0, 0, 0);
    }

    float bv[4];
#pragma unroll
    for (int j = 0; j < 4; ++j)
        bv[j] = bias[colBase + wc * 64 + j * 16 + l16];
#pragma unroll
    for (int i = 0; i < 4; ++i) {
#pragma unroll
        for (int r = 0; r < 4; ++r) {
            int row = rowBase + wr * 64 + i * 16 + quad * 4 + r;
            OutT* yp = Y + (size_t)row * N + colBase + wc * 64 + l16;
            float s = 0.f;
#pragma unroll
            for (int j = 0; j < 4; ++j) {
                float v = acc[i][j][r] + bv[j];
                s += v * v;
                yp[j * 16] = (OutT)v;
            }
            s += __shfl_xor(s, 1);
            s += __shfl_xor(s, 2);
            s += __shfl_xor(s, 4);
            s += __shfl_xor(s, 8);
            if (l16 == 0) atomicAdd(&ssq[row], s);
        }
    }
}

// ---------------------------------------------------------------------------
__global__ __launch_bounds__(256) void k_invr(float* ssq, int n, float invD)
{
    int i = blockIdx.x * 256 + threadIdx.x;
    if (i < n) ssq[i] = rsqrtf(ssq[i] * invD + 1e-12f);
}

__global__ __launch_bounds__(256) void k_final(
    const float* __restrict__ Y2, const float* __restrict__ ssq2,
    const float* __restrict__ G2, float* __restrict__ out)
{
    int gidx = blockIdx.x * 256 + threadIdx.x;  // vec4 index over M*256/4
    int r = gidx >> 6;
    int c = (gidx & 63) * 4;
    float inv = rsqrtf(ssq2[r] * (1.f / DOUT) + 1e-12f);
    f32x4 yv = *(const f32x4*)&Y2[(size_t)r * DOUT + c];
    f32x4 o;
#pragma unroll
    for (int j = 0; j < 4; ++j) {
        float v = G2[c + j] * yv[j] * inv;
        o[j] = v > 0.f ? v : 0.f;
    }
    *(f32x4*)&out[(size_t)r * DOUT + c] = o;
}

// transpose + cast: in fp32 [R][C] -> out bf16 [C][R]
__global__ __launch_bounds__(256) void k_castT(
    const float* __restrict__ in, bf16* __restrict__ out, int R, int C)
{
    int idx = blockIdx.x * 256 + threadIdx.x;
    if (idx < R * C) {
        int c = idx / R, r = idx - c * R;
        out[idx] = (bf16)in[r * C + c];
    }
}

// ---------------------------------------------------------------------------
extern "C" void kernel_launch(void* const* d_in, const int* in_sizes, int n_in,
                              void* d_out, int out_size, void* d_ws, size_t ws_size,
                              hipStream_t stream)
{
    const float* table = (const float*)d_in[0];
    const float* asim  = (const float*)d_in[1];
    const float* tsim  = (const float*)d_in[2];
    const float* adj   = (const float*)d_in[3];
    const float* W1    = (const float*)d_in[4];
    const float* b1    = (const float*)d_in[5];
    const float* g1    = (const float*)d_in[6];
    const float* W2    = (const float*)d_in[7];
    const float* b2    = (const float*)d_in[8];
    const float* g2    = (const float*)d_in[9];
    float* out = (float*)d_out;

    char* ws = (char*)d_ws;
    const size_t SZ_X = (size_t)MROWS * DIN * 2;          // 113246208 bytes
    bf16*  X    = (bf16*)ws;                               // [M,768] bf16
    bf16*  Y1   = (bf16*)(ws + SZ_X);                      // [M,768] bf16
    float* Y2   = (float*)(ws + SZ_X);                     // [M,256] f32 (aliases Y1; Y1 dead)
    bf16*  W1T  = (bf16*)(ws + 2 * SZ_X);
    bf16*  W2T  = (bf16*)(ws + 2 * SZ_X + 1179648);
    float* ssq1 = (float*)(ws + 2 * SZ_X + 1179648 + 393216);
    float* ssq2 = ssq1 + MROWS;

    hipMemsetAsync(ssq1, 0, (size_t)MROWS * 4 * 2, stream);
    k_castT<<<2304, 256, 0, stream>>>(W1, W1T, DIN, DIN);
    k_castT<<<768, 256, 0, stream>>>(W2, W2T, DIN, DOUT);

    k_gether1<<<8 * S, 256, 0, stream>>>(table, asim, tsim, adj, X);
    k_gemm<DIN, bf16><<<dim3(DIN / 128, MROWS / 128), 256, 0, stream>>>(X, W1T, b1, Y1, ssq1);
    k_invr<<<MROWS / 256, 256, 0, stream>>>(ssq1, MROWS, 1.f / DIN);
    k_gether2<<<8 * S, 256, 0, stream>>>(Y1, ssq1, g1, asim, tsim, adj, X);
    k_gemm<DOUT, float><<<dim3(DOUT / 128, MROWS / 128), 256, 0, stream>>>(X, W2T, b2, Y2, ssq2);
    k_final<<<(MROWS * DOUT / 4) / 256, 256, 0, stream>>>(Y2, ssq2, g2, out);
}

// Round 3
// 693.571 us; speedup vs baseline: 1.0097x; 1.0097x over previous
//
#include <hip/hip_runtime.h>

typedef __bf16 bf16;
typedef __bf16 bf16x4 __attribute__((ext_vector_type(4)));
typedef __bf16 bf16x8 __attribute__((ext_vector_type(8)));
typedef float f32x4 __attribute__((ext_vector_type(4)));
typedef float floatx4 __attribute__((ext_vector_type(4)));

#define S 96
#define DIN 768
#define DOUT 256
#define MROWS 73728  // 8*96*96

__device__ static inline void async16(const bf16* g, bf16* l) {
    __builtin_amdgcn_global_load_lds(
        (const __attribute__((address_space(1))) void*)g,
        (__attribute__((address_space(3))) void*)l,
        16, 0, 0);
}

// ---------------------------------------------------------------------------
// gether1: X = gether(H) + H  (coefficient 2 on center row). fp32 in, bf16 out
// ---------------------------------------------------------------------------
__global__ __launch_bounds__(256) void k_gether1(
    const float* __restrict__ H, const float* __restrict__ Asim,
    const float* __restrict__ Tsim, const float* __restrict__ Adj,
    bf16* __restrict__ X)
{
    __shared__ float adjs[S];
    __shared__ float ts[S];
    __shared__ float diagf[DIN];
    int b = blockIdx.x / S, l = blockIdx.x % S;
    int tid = threadIdx.x;
    long row0 = (long)(b * S + l) * S;
    if (tid < S) {
        adjs[tid] = Adj[(b * S + l) * S + tid];
        ts[tid]   = Tsim[b * S + tid];
    }
    for (int i = tid; i < DIN / 4; i += 256)
        *(f32x4*)&diagf[i * 4] = *(const f32x4*)&H[(row0 + l) * DIN + i * 4];
    float a_up = (l > 0)     ? Asim[b * S + l - 1] : 0.f;
    float a_dn = (l < S - 1) ? Asim[b * S + l + 1] : 0.f;
    long du = (l > 0)     ? -(long)S * DIN : 0;
    long dd = (l < S - 1) ?  (long)S * DIN : 0;
    __syncthreads();

    for (int it = tid; it < S * (DIN / 4); it += 256) {
        int k = it / (DIN / 4);
        int c = it - k * (DIN / 4);
        const float* hc = H + (row0 + k) * DIN + c * 4;
        float tl = (k > 0)     ? ts[k - 1] : 0.f;
        float tr = (k < S - 1) ? ts[k + 1] : 0.f;
        long  dl = (k > 0)     ? -(long)DIN : 0;
        long  dr = (k < S - 1) ?  (long)DIN : 0;
        f32x4 vc = *(const f32x4*)hc;
        f32x4 vl = *(const f32x4*)(hc + dl);
        f32x4 vr = *(const f32x4*)(hc + dr);
        f32x4 vu = *(const f32x4*)(hc + du);
        f32x4 vd = *(const f32x4*)(hc + dd);
        float aj = adjs[k];
        bf16x4 o;
#pragma unroll
        for (int j = 0; j < 4; ++j) {
            float v = 2.f * vc[j] + aj * diagf[c * 4 + j]
                    + tl * vl[j] + tr * vr[j]
                    + a_up * vu[j] + a_dn * vd[j];
            o[j] = (bf16)v;
        }
        *(bf16x4*)&X[(row0 + k) * DIN + c * 4] = o;
    }
}

// ---------------------------------------------------------------------------
// gether2: sources are h1 = relu(g1 * y * invr) reconstructed on the fly.
// ---------------------------------------------------------------------------
__global__ __launch_bounds__(256) void k_gether2(
    const bf16* __restrict__ Y, const float* __restrict__ INV,
    const float* __restrict__ G1, const float* __restrict__ Asim,
    const float* __restrict__ Tsim, const float* __restrict__ Adj,
    bf16* __restrict__ X)
{
    __shared__ float adjs[S];
    __shared__ float ts[S];
    __shared__ float diagf[DIN];
    __shared__ float g1s[DIN];
    int b = blockIdx.x / S, l = blockIdx.x % S;
    int tid = threadIdx.x;
    long row0 = (long)(b * S + l) * S;
    for (int i = tid; i < DIN; i += 256) g1s[i] = G1[i];
    __syncthreads();
    if (tid < S) {
        adjs[tid] = Adj[(b * S + l) * S + tid];
        ts[tid]   = Tsim[b * S + tid];
        float iv = INV[row0 + l];
        bf16x8 yv = *(const bf16x8*)&Y[(row0 + l) * DIN + tid * 8];
#pragma unroll
        for (int j = 0; j < 8; ++j) {
            float v = g1s[tid * 8 + j] * (float)yv[j] * iv;
            diagf[tid * 8 + j] = v > 0.f ? v : 0.f;
        }
    }
    float a_up = (l > 0)     ? Asim[b * S + l - 1] : 0.f;
    float a_dn = (l < S - 1) ? Asim[b * S + l + 1] : 0.f;
    long du = (l > 0)     ? -(long)S * DIN : 0;
    long dd = (l < S - 1) ?  (long)S * DIN : 0;
    int ou = (l > 0) ? -S : 0;
    int od = (l < S - 1) ? S : 0;
    __syncthreads();

    for (int it = tid; it < S * (DIN / 8); it += 256) {
        int k = it / (DIN / 8);
        int c = it - k * (DIN / 8);
        const bf16* yc = Y + (row0 + k) * DIN + c * 8;
        float tl = (k > 0)     ? ts[k - 1] : 0.f;
        float tr = (k < S - 1) ? ts[k + 1] : 0.f;
        int   ol = (k > 0)     ? -1 : 0;
        int   orr = (k < S - 1) ? 1 : 0;
        float ivc = INV[row0 + k];
        float ivl = INV[row0 + k + ol];
        float ivr = INV[row0 + k + orr];
        float ivu = INV[row0 + k + ou];
        float ivd = INV[row0 + k + od];
        bf16x8 vc = *(const bf16x8*)yc;
        bf16x8 vl = *(const bf16x8*)(yc + (long)ol * DIN);
        bf16x8 vr = *(const bf16x8*)(yc + (long)orr * DIN);
        bf16x8 vu = *(const bf16x8*)(yc + du);
        bf16x8 vd = *(const bf16x8*)(yc + dd);
        float aj = adjs[k];
        bf16x8 o;
#pragma unroll
        for (int j = 0; j < 8; ++j) {
            float g = g1s[c * 8 + j];
            float hc_ = g * (float)vc[j] * ivc; hc_ = hc_ > 0.f ? hc_ : 0.f;
            float hl_ = g * (float)vl[j] * ivl; hl_ = hl_ > 0.f ? hl_ : 0.f;
            float hr_ = g * (float)vr[j] * ivr; hr_ = hr_ > 0.f ? hr_ : 0.f;
            float hu_ = g * (float)vu[j] * ivu; hu_ = hu_ > 0.f ? hu_ : 0.f;
            float hd_ = g * (float)vd[j] * ivd; hd_ = hd_ > 0.f ? hd_ : 0.f;
            float v = 2.f * hc_ + aj * diagf[c * 8 + j]
                    + tl * hl_ + tr * hr_ + a_up * hu_ + a_dn * hd_;
            o[j] = (bf16)v;
        }
        *(bf16x8*)&X[(row0 + k) * DIN + c * 8] = o;
    }
}

// ---------------------------------------------------------------------------
// GEMM1: Y[M x 768] = X @ W1T^T + b1 (bf16 out), ssq accumulate.
// 128x192 tile, BK=32, 4 waves as 2x2, each 64x96 (4x6 frags 16x16x32).
// LDS XOR-swizzled: stage chunk (t&3)^((t>>3)&3); read slot quad^((row>>1)&3).
// grid = (rowTiles=576, colTiles=4): x fastest -> each col pass streams X (LLC)
// ---------------------------------------------------------------------------
__global__ __launch_bounds__(256) void k_gemm1(
    const bf16* __restrict__ Xm, const bf16* __restrict__ WT,
    const float* __restrict__ bias, bf16* __restrict__ Y,
    float* __restrict__ ssq)
{
    constexpr int K = 768, N = 768;
    __shared__ __align__(16) bf16 As[128 * 32];
    __shared__ __align__(16) bf16 Bs[192 * 32];
    int t = threadIdx.x;
    int rowBase = blockIdx.x * 128;
    int colBase = blockIdx.y * 192;
    int lane = t & 63, w = t >> 6;
    int quad = lane >> 4, l16 = lane & 15;
    int wr = w >> 1, wc = w & 1;

    floatx4 acc[4][6];
#pragma unroll
    for (int i = 0; i < 4; ++i)
#pragma unroll
        for (int j = 0; j < 6; ++j) acc[i][j] = (floatx4)0.f;

    int chunk = (t & 3) ^ ((t >> 3) & 3);   // staged (swizzled) k-chunk
    const bf16* gA = Xm + (size_t)(rowBase + (t >> 2)) * K + chunk * 8;
    const bf16* gB = WT + (size_t)(colBase + (t >> 2)) * K + chunk * 8;
    bf16* ldsA = &As[t * 8];
    bf16* ldsB = &Bs[t * 8];

    for (int kk = 0; kk < K; kk += 32) {
        __syncthreads();
        async16(gA + kk, ldsA);
        async16(gA + kk + 64 * K, ldsA + 2048);
        async16(gB + kk, ldsB);
        async16(gB + kk + 64 * K, ldsB + 2048);
        async16(gB + kk + 128 * K, ldsB + 4096);
        __syncthreads();
        bf16x8 af[4], bfr[6];
#pragma unroll
        for (int i = 0; i < 4; ++i) {
            int ra = wr * 64 + i * 16 + l16;
            af[i] = *(const bf16x8*)&As[ra * 32 + (quad ^ ((ra >> 1) & 3)) * 8];
        }
#pragma unroll
        for (int j = 0; j < 6; ++j) {
            int rb = wc * 96 + j * 16 + l16;
            bfr[j] = *(const bf16x8*)&Bs[rb * 32 + (quad ^ ((rb >> 1) & 3)) * 8];
        }
#pragma unroll
        for (int i = 0; i < 4; ++i)
#pragma unroll
            for (int j = 0; j < 6; ++j)
                acc[i][j] = __builtin_amdgcn_mfma_f32_16x16x32_bf16(
                    af[i], bfr[j], acc[i][j], 0, 0, 0);
    }

    float bv[6];
#pragma unroll
    for (int j = 0; j < 6; ++j)
        bv[j] = bias[colBase + wc * 96 + j * 16 + l16];
#pragma unroll
    for (int i = 0; i < 4; ++i) {
#pragma unroll
        for (int r = 0; r < 4; ++r) {
            int row = rowBase + wr * 64 + i * 16 + quad * 4 + r;
            bf16* yp = Y + (size_t)row * N + colBase + wc * 96 + l16;
            float s = 0.f;
#pragma unroll
            for (int j = 0; j < 6; ++j) {
                float v = acc[i][j][r] + bv[j];
                s += v * v;
                yp[j * 16] = (bf16)v;
            }
            s += __shfl_xor(s, 1);
            s += __shfl_xor(s, 2);
            s += __shfl_xor(s, 4);
            s += __shfl_xor(s, 8);
            if (l16 == 0) atomicAdd(&ssq[row], s);
        }
    }
}

// ---------------------------------------------------------------------------
// GEMM2: Y2[M x 256] = X2 @ W2T^T + b2 (f32 out), ssq accumulate.
// 128x128 tile (4x4 frags), swizzled LDS. grid (576, 2) x fastest.
// ---------------------------------------------------------------------------
__global__ __launch_bounds__(256) void k_gemm2(
    const bf16* __restrict__ Xm, const bf16* __restrict__ WT,
    const float* __restrict__ bias, float* __restrict__ Y,
    float* __restrict__ ssq)
{
    constexpr int K = 768, N = 256;
    __shared__ __align__(16) bf16 As[128 * 32];
    __shared__ __align__(16) bf16 Bs[128 * 32];
    int t = threadIdx.x;
    int rowBase = blockIdx.x * 128;
    int colBase = blockIdx.y * 128;
    int lane = t & 63, w = t >> 6;
    int quad = lane >> 4, l16 = lane & 15;
    int wr = w >> 1, wc = w & 1;

    floatx4 acc[4][4];
#pragma unroll
    for (int i = 0; i < 4; ++i)
#pragma unroll
        for (int j = 0; j < 4; ++j) acc[i][j] = (floatx4)0.f;

    int chunk = (t & 3) ^ ((t >> 3) & 3);
    const bf16* gA = Xm + (size_t)(rowBase + (t >> 2)) * K + chunk * 8;
    const bf16* gB = WT + (size_t)(colBase + (t >> 2)) * K + chunk * 8;
    bf16* ldsA = &As[t * 8];
    bf16* ldsB = &Bs[t * 8];

    for (int kk = 0; kk < K; kk += 32) {
        __syncthreads();
        async16(gA + kk, ldsA);
        async16(gA + kk + 64 * K, ldsA + 2048);
        async16(gB + kk, ldsB);
        async16(gB + kk + 64 * K, ldsB + 2048);
        __syncthreads();
        bf16x8 af[4], bfr[4];
#pragma unroll
        for (int i = 0; i < 4; ++i) {
            int ra = wr * 64 + i * 16 + l16;
            af[i] = *(const bf16x8*)&As[ra * 32 + (quad ^ ((ra >> 1) & 3)) * 8];
        }
#pragma unroll
        for (int j = 0; j < 4; ++j) {
            int rb = wc * 64 + j * 16 + l16;
            bfr[j] = *(const bf16x8*)&Bs[rb * 32 + (quad ^ ((rb >> 1) & 3)) * 8];
        }
#pragma unroll
        for (int i = 0; i < 4; ++i)
#pragma unroll
            for (int j = 0; j < 4; ++j)
                acc[i][j] = __builtin_amdgcn_mfma_f32_16x16x32_bf16(
                    af[i], bfr[j], acc[i][j], 0, 0, 0);
    }

    float bv[4];
#pragma unroll
    for (int j = 0; j < 4; ++j)
        bv[j] = bias[colBase + wc * 64 + j * 16 + l16];
#pragma unroll
    for (int i = 0; i < 4; ++i) {
#pragma unroll
        for (int r = 0; r < 4; ++r) {
            int row = rowBase + wr * 64 + i * 16 + quad * 4 + r;
            float* yp = Y + (size_t)row * N + colBase + wc * 64 + l16;
            float s = 0.f;
#pragma unroll
            for (int j = 0; j < 4; ++j) {
                float v = acc[i][j][r] + bv[j];
                s += v * v;
                yp[j * 16] = v;
            }
            s += __shfl_xor(s, 1);
            s += __shfl_xor(s, 2);
            s += __shfl_xor(s, 4);
            s += __shfl_xor(s, 8);
            if (l16 == 0) atomicAdd(&ssq[row], s);
        }
    }
}

// ---------------------------------------------------------------------------
__global__ __launch_bounds__(256) void k_invr(float* ssq, int n, float invD)
{
    int i = blockIdx.x * 256 + threadIdx.x;
    if (i < n) ssq[i] = rsqrtf(ssq[i] * invD + 1e-12f);
}

__global__ __launch_bounds__(256) void k_final(
    const float* __restrict__ Y2, const float* __restrict__ ssq2,
    const float* __restrict__ G2, float* __restrict__ out)
{
    int gidx = blockIdx.x * 256 + threadIdx.x;
    int r = gidx >> 6;
    int c = (gidx & 63) * 4;
    float inv = rsqrtf(ssq2[r] * (1.f / DOUT) + 1e-12f);
    f32x4 yv = *(const f32x4*)&Y2[(size_t)r * DOUT + c];
    f32x4 o;
#pragma unroll
    for (int j = 0; j < 4; ++j) {
        float v = G2[c + j] * yv[j] * inv;
        o[j] = v > 0.f ? v : 0.f;
    }
    *(f32x4*)&out[(size_t)r * DOUT + c] = o;
}

// tiled transpose + cast: in fp32 [R][C] -> out bf16 [C][R]; grid (C/32, R/32)
__global__ __launch_bounds__(256) void k_castT(
    const float* __restrict__ in, bf16* __restrict__ out, int R, int C)
{
    __shared__ float tile[32][33];
    int lx = threadIdx.x & 31, ly = threadIdx.x >> 5;  // ly 0..7
    int c0 = blockIdx.x * 32, r0 = blockIdx.y * 32;
#pragma unroll
    for (int k = 0; k < 4; ++k)
        tile[ly + 8 * k][lx] = in[(size_t)(r0 + ly + 8 * k) * C + c0 + lx];
    __syncthreads();
#pragma unroll
    for (int k = 0; k < 4; ++k)
        out[(size_t)(c0 + ly + 8 * k) * R + r0 + lx] = (bf16)tile[lx][ly + 8 * k];
}

// ---------------------------------------------------------------------------
extern "C" void kernel_launch(void* const* d_in, const int* in_sizes, int n_in,
                              void* d_out, int out_size, void* d_ws, size_t ws_size,
                              hipStream_t stream)
{
    const float* table = (const float*)d_in[0];
    const float* asim  = (const float*)d_in[1];
    const float* tsim  = (const float*)d_in[2];
    const float* adj   = (const float*)d_in[3];
    const float* W1    = (const float*)d_in[4];
    const float* b1    = (const float*)d_in[5];
    const float* g1    = (const float*)d_in[6];
    const float* W2    = (const float*)d_in[7];
    const float* b2    = (const float*)d_in[8];
    const float* g2    = (const float*)d_in[9];
    float* out = (float*)d_out;

    char* ws = (char*)d_ws;
    const size_t SZ_X = (size_t)MROWS * DIN * 2;          // 113246208 bytes
    bf16*  X    = (bf16*)ws;                               // [M,768] bf16
    bf16*  Y1   = (bf16*)(ws + SZ_X);                      // [M,768] bf16
    float* Y2   = (float*)(ws + SZ_X);                     // [M,256] f32 (aliases Y1)
    bf16*  W1T  = (bf16*)(ws + 2 * SZ_X);
    bf16*  W2T  = (bf16*)(ws + 2 * SZ_X + 1179648);
    float* ssq1 = (float*)(ws + 2 * SZ_X + 1179648 + 393216);
    float* ssq2 = ssq1 + MROWS;

    hipMemsetAsync(ssq1, 0, (size_t)MROWS * 4 * 2, stream);
    k_castT<<<dim3(DIN / 32, DIN / 32), 256, 0, stream>>>(W1, W1T, DIN, DIN);
    k_castT<<<dim3(DOUT / 32, DIN / 32), 256, 0, stream>>>(W2, W2T, DIN, DOUT);

    k_gether1<<<8 * S, 256, 0, stream>>>(table, asim, tsim, adj, X);
    k_gemm1<<<dim3(MROWS / 128, DIN / 192), 256, 0, stream>>>(X, W1T, b1, Y1, ssq1);
    k_invr<<<MROWS / 256, 256, 0, stream>>>(ssq1, MROWS, 1.f / DIN);
    k_gether2<<<8 * S, 256, 0, stream>>>(Y1, ssq1, g1, asim, tsim, adj, X);
    k_gemm2<<<dim3(MROWS / 128, DOUT / 128), 256, 0, stream>>>(X, W2T, b2, Y2, ssq2);
    k_final<<<(MROWS * DOUT / 4) / 256, 256, 0, stream>>>(Y2, ssq2, g2, out);
}